// Round 8
// baseline (1033.727 us; speedup 1.0000x reference)
//
#include <hip/hip_runtime.h>
#include <hip/hip_bf16.h>
#include <math.h>

typedef __attribute__((ext_vector_type(8))) short bf8_t;   // 8 x bf16 (4 VGPRs)
typedef __attribute__((ext_vector_type(4))) float f4_t;    // MFMA accumulator
typedef __attribute__((ext_vector_type(8))) unsigned short us8_t;

__device__ inline unsigned short f2bf(float f) {
  union { float f; unsigned u; } x; x.f = f;
  unsigned r = x.u + 0x7FFF + ((x.u >> 16) & 1);   // RNE
  return (unsigned short)(r >> 16);
}
__device__ inline float bflo(unsigned v) {
  union { unsigned u; float f; } x; x.u = v << 16; return x.f;
}
__device__ inline float bfhi(unsigned v) {
  union { unsigned u; float f; } x; x.u = v & 0xFFFF0000u; return x.f;
}
__device__ inline float fast_sig(float x) {
  return __builtin_amdgcn_rcpf(1.f + __expf(-x));
}
__device__ inline float fast_tanh(float x) {
  return 1.f - 2.f * __builtin_amdgcn_rcpf(1.f + __expf(2.f * x));
}

// async global->LDS copy, 16B per lane; LDS dest = base + lane*16 (HW rule)
__device__ inline void async_copy16(const void* g, void* l) {
  __builtin_amdgcn_global_load_lds(
      (const __attribute__((address_space(1))) unsigned int*)g,
      (__attribute__((address_space(3))) unsigned int*)l, 16, 0, 0);
}

__device__ inline bf8_t pack_bf8(const float* p) {
  float4 a = *(const float4*)p;
  float4 b = *(const float4*)(p + 4);
  bf8_t t;
  t[0] = (short)f2bf(a.x); t[1] = (short)f2bf(a.y);
  t[2] = (short)f2bf(a.z); t[3] = (short)f2bf(a.w);
  t[4] = (short)f2bf(b.x); t[5] = (short)f2bf(b.y);
  t[6] = (short)f2bf(b.z); t[7] = (short)f2bf(b.w);
  return t;
}

// ---------------------------------------------------------------------------
// device bodies
// ---------------------------------------------------------------------------

// pack weight matrix into MFMA B-fragment order (16x16x32 bf16).
__device__ inline void packB_body(const float* __restrict__ W,
                                  unsigned short* __restrict__ out,
                                  int K, int Ncols, int ldw, int trans, int bid) {
  int idx = bid * 256 + threadIdx.x;
  int total = (Ncols / 16) * (K / 32) * 64;
  if (idx >= total) return;
  int lane = idx & 63;
  int frag = idx >> 6;
  int kt = K / 32;
  int k0 = frag % kt;
  int n0 = frag / kt;
  int n = n0 * 16 + (lane & 15);
  int kbase = k0 * 32 + (lane >> 4) * 8;
  us8_t v;
#pragma unroll
  for (int j = 0; j < 8; ++j) {
    int k = kbase + j;
    float f = trans ? W[(size_t)n * ldw + k] : W[(size_t)k * ldw + n];
    v[j] = f2bf(f);
  }
  *(us8_t*)(out + (size_t)idx * 8) = v;
}

// atomic-free CSR fill (slot from pos[]), raw weight, NT store. 512-wide bid.
__device__ inline void fill_body(const int* __restrict__ src, const int* __restrict__ dst,
                                 const float* __restrict__ ew, const int* __restrict__ rowptr,
                                 const int* __restrict__ pos, int2* __restrict__ csr,
                                 int E, int bid) {
  // 256-thr blocks: 2 edges per thread
#pragma unroll
  for (int t = 0; t < 2; ++t) {
    int e = bid * 512 + t * 256 + threadIdx.x;
    if (e < E) {
      int d = dst[e];
      int p = rowptr[d] + pos[e];
      unsigned long long v = (unsigned long long)(unsigned)src[e] |
                             ((unsigned long long)(unsigned)__float_as_int(ew[e]) << 32);
      __builtin_nontemporal_store(v, (unsigned long long*)(csr + p));
    }
  }
}

// deg[n] = 1 + sum raw incoming ew; dinv = rsqrt. 512-wide bid (2 nodes/thr).
__device__ inline void deg_body(const int* __restrict__ rowptr, const int2* __restrict__ csr,
                                float* __restrict__ dinv, int N, int bid) {
#pragma unroll
  for (int t = 0; t < 2; ++t) {
    int n = bid * 512 + t * 256 + threadIdx.x;
    if (n < N) {
      int b = rowptr[n], e = rowptr[n + 1];
      float s = 1.0f;
      for (int j = b; j < e; ++j) {
        unsigned long long v = __builtin_nontemporal_load((const unsigned long long*)(csr + j));
        s += __int_as_float((int)(v >> 32));
      }
      dinv[n] = rsqrtf(s);
    }
  }
}

// MFMA GEMM body, 4 waves x 16 rows = 64 rows/block; 32KB smem.
// F32A: A is fp32, converted to bf16 in-register at load.
template<bool RELU, bool BIAS, bool F32A>
__device__ inline void gemm_body4(const void* __restrict__ Araw,
                                  const unsigned short* __restrict__ Bp,
                                  const float* __restrict__ bias,
                                  unsigned short* __restrict__ C, int M, int bid,
                                  unsigned char* smem) {
  int wave = threadIdx.x >> 6, lane = threadIdx.x & 63;
  int row0 = (bid * 4 + wave) * 16;
  int m = lane & 15, q = lane >> 4;

#pragma unroll
  for (int i = 0; i < 8; ++i) {
    int f = wave * 8 + i;
    async_copy16((const unsigned char*)Bp + (size_t)f * 1024 + lane * 16,
                 smem + f * 1024);
  }
  __syncthreads();
  if (row0 >= M) return;

  int arow = row0 + m; if (arow >= M) arow = M - 1;
  bf8_t a[4];
#pragma unroll
  for (int k0 = 0; k0 < 4; ++k0) {
    if (F32A) {
      a[k0] = pack_bf8((const float*)Araw + (size_t)arow * 128 + k0 * 32 + q * 8);
    } else {
      a[k0] = *(const bf8_t*)((const unsigned short*)Araw +
                              (size_t)arow * 128 + k0 * 32 + q * 8);
    }
  }

#pragma unroll
  for (int n0 = 0; n0 < 8; ++n0) {
    f4_t acc = {};
#pragma unroll
    for (int k0 = 0; k0 < 4; ++k0) {
      bf8_t b = *(const bf8_t*)(smem + (n0 * 4 + k0) * 1024 + lane * 16);
      acc = __builtin_amdgcn_mfma_f32_16x16x32_bf16(a[k0], b, acc, 0, 0, 0);
    }
    int col = n0 * 16 + m;
    float bs = BIAS ? bias[col] : 0.f;
#pragma unroll
    for (int r = 0; r < 4; ++r) {
      int grow = row0 + q * 4 + r;
      if (grow < M) {
        float v = acc[r] + bs;
        if (RELU) v = fmaxf(v, 0.f);
        C[(size_t)grow * 128 + col] = f2bf(v);
      }
    }
  }
}

// GRU B-staging, 4 waves: wave stages 6 of 24 frags into one 24KB half
__device__ inline void gru_stage4(const unsigned short* __restrict__ Bi,
                                  const unsigned short* __restrict__ Bh,
                                  unsigned char* half, int wave, int lane, int g) {
#pragma unroll
  for (int s = 0; s < 6; ++s) {
    int cc = g + 8 * (s >= 3 ? s - 3 : s);
    const unsigned short* src = (s < 3) ? Bi : Bh;
    int f = s * 4 + wave;
    async_copy16((const unsigned char*)src + ((size_t)(cc * 4 + wave)) * 1024 + lane * 16,
                 half + f * 1024);
  }
}

// GRU core, 4 waves, DOUBLE-BUFFERED staging (smem = 2 x 24KB).
// In-place h safe; fully unrolled (static indices, no scratch).
__device__ inline void gru_core4(const bf8_t* ax, const float* h_in, float* h_out,
                                 const unsigned short* __restrict__ Bi,
                                 const unsigned short* __restrict__ Bh,
                                 const float* __restrict__ bih, const float* __restrict__ bhh,
                                 int M, int row0, int wave, int lane,
                                 unsigned char* smem) {
  int m = lane & 15, q = lane >> 4;
  int arow = row0 + m; if (arow >= M) arow = M - 1;

  bf8_t ah[4];
#pragma unroll
  for (int k0 = 0; k0 < 4; ++k0)
    ah[k0] = pack_bf8(h_in + (size_t)arow * 128 + k0 * 32 + q * 8);

  int erow[4];
#pragma unroll
  for (int r = 0; r < 4; ++r) {
    int gr = row0 + q * 4 + r;
    erow[r] = (gr < M) ? gr : (M - 1);
  }

  float hp_cur[4], hp_nxt[4];
#pragma unroll
  for (int r = 0; r < 4; ++r)
    hp_cur[r] = h_in[(size_t)erow[r] * 128 + m];

#pragma unroll
  for (int g = 0; g < 8; ++g) {
    __syncthreads();   // stage(g) complete; prev group's LDS reads all done
    if (g < 7)         // issue next stage NOW -> hides under MFMA + epilogue
      gru_stage4(Bi, Bh, smem + ((g + 1) & 1) * (24 * 1024), wave, lane, g + 1);
    unsigned char* cur = smem + (g & 1) * (24 * 1024);

    f4_t air = {}, aiz = {}, ain = {}, ahr = {}, ahz = {}, ahn = {};
#pragma unroll
    for (int k0 = 0; k0 < 4; ++k0) {
      bf8_t br = *(const bf8_t*)(cur + (0 * 4 + k0) * 1024 + lane * 16);
      bf8_t bz = *(const bf8_t*)(cur + (1 * 4 + k0) * 1024 + lane * 16);
      bf8_t bn = *(const bf8_t*)(cur + (2 * 4 + k0) * 1024 + lane * 16);
      bf8_t cr = *(const bf8_t*)(cur + (3 * 4 + k0) * 1024 + lane * 16);
      bf8_t cz = *(const bf8_t*)(cur + (4 * 4 + k0) * 1024 + lane * 16);
      bf8_t cn = *(const bf8_t*)(cur + (5 * 4 + k0) * 1024 + lane * 16);
      air = __builtin_amdgcn_mfma_f32_16x16x32_bf16(ax[k0], br, air, 0, 0, 0);
      aiz = __builtin_amdgcn_mfma_f32_16x16x32_bf16(ax[k0], bz, aiz, 0, 0, 0);
      ain = __builtin_amdgcn_mfma_f32_16x16x32_bf16(ax[k0], bn, ain, 0, 0, 0);
      ahr = __builtin_amdgcn_mfma_f32_16x16x32_bf16(ah[k0], cr, ahr, 0, 0, 0);
      ahz = __builtin_amdgcn_mfma_f32_16x16x32_bf16(ah[k0], cz, ahz, 0, 0, 0);
      ahn = __builtin_amdgcn_mfma_f32_16x16x32_bf16(ah[k0], cn, ahn, 0, 0, 0);
    }
    if (g < 7) {                         // issue next group's hprev loads
#pragma unroll
      for (int r = 0; r < 4; ++r)
        hp_nxt[r] = h_in[(size_t)erow[r] * 128 + (g + 1) * 16 + m];
    }

    int col = g * 16 + m;
    float bir_ = bih[col], biz_ = bih[col + 128], bin_ = bih[col + 256];
    float bhr_ = bhh[col], bhz_ = bhh[col + 128], bhn_ = bhh[col + 256];
#pragma unroll
    for (int r = 0; r < 4; ++r) {
      int grow = row0 + q * 4 + r;
      if (grow < M) {
        float rr = fast_sig(air[r] + bir_ + ahr[r] + bhr_);
        float zz = fast_sig(aiz[r] + biz_ + ahz[r] + bhz_);
        float nn = fast_tanh(ain[r] + bin_ + rr * (ahn[r] + bhn_));
        h_out[(size_t)grow * 128 + col] = (1.f - zz) * nn + zz * hp_cur[r];
      }
    }
#pragma unroll
    for (int r = 0; r < 4; ++r) hp_cur[r] = hp_nxt[r];
  }
}

// full GRU body for one 4-wave block (reads ax from global bf16 xh)
__device__ inline void gru_body4(const unsigned short* __restrict__ xh,
                                 const float* h_in, float* h_out,
                                 const unsigned short* __restrict__ Bi,
                                 const unsigned short* __restrict__ Bh,
                                 const float* __restrict__ bih, const float* __restrict__ bhh,
                                 int M, int bid, unsigned char* smem) {
  int wave = threadIdx.x >> 6, lane = threadIdx.x & 63;
  int row0 = (bid * 4 + wave) * 16;
  gru_stage4(Bi, Bh, smem, wave, lane, 0);
  int m = lane & 15, q = lane >> 4;
  int arow = row0 + m; if (arow >= M) arow = M - 1;
  bf8_t ax[4];
#pragma unroll
  for (int k0 = 0; k0 < 4; ++k0)
    ax[k0] = *(const bf8_t*)(xh + (size_t)arow * 128 + k0 * 32 + q * 8);
  gru_core4(ax, h_in, h_out, Bi, Bh, bih, bhh, M, row0, wave, lane, smem);
}

// ---------------------------------------------------------------------------
// kernels
// ---------------------------------------------------------------------------

// prep: all 6 weight packs + zero cnt, one launch (256 thr)
__global__ __launch_bounds__(256) void k_prep(
    const float* __restrict__ linW, const float* __restrict__ convW,
    const float* __restrict__ Wih, const float* __restrict__ Whh,
    unsigned short* __restrict__ linWp, unsigned short* __restrict__ convWp,
    unsigned short* __restrict__ Bi, unsigned short* __restrict__ Bh,
    int* __restrict__ cnt, int N) {
  int b = blockIdx.x;
  if (b < 8)  { packB_body(linW, linWp, 128, 128, 128, 0, b); return; }
  if (b < 32) { int l = (b - 8) >> 3;
                packB_body(convW + (size_t)l * 16384, convWp + (size_t)l * 16384,
                           128, 128, 128, 0, (b - 8) & 7); return; }
  if (b < 56) { packB_body(Wih, Bi, 128, 384, 128, 1, b - 32); return; }
  if (b < 80) { packB_body(Whh, Bh, 128, 384, 128, 1, b - 56); return; }
  int i = (b - 80) * 256 + threadIdx.x;
  if (i < N) cnt[i] = 0;
}

// fused: atomic histogram+pos (blocks [0,nCnt)) || lin GEMM from fp32 x
__global__ __launch_bounds__(256) void k_count_lin(
    const int* __restrict__ dst, int* __restrict__ cnt, int* __restrict__ pos, int E,
    const float* __restrict__ x, const unsigned short* __restrict__ linWp,
    const float* __restrict__ linB, unsigned short* __restrict__ xh, int M,
    int nCnt) {
  __shared__ unsigned char smem[32 * 1024];
  if ((int)blockIdx.x < nCnt) {
    int e = blockIdx.x * 256 + threadIdx.x;
    if (e < E) pos[e] = atomicAdd(&cnt[dst[e]], 1);
    return;
  }
  gemm_body4<true, true, true>(x, linWp, linB, xh, M, blockIdx.x - nCnt, smem);
}

// hierarchical scan for rowptr
__global__ __launch_bounds__(256) void k_scan_block(
    const int* __restrict__ cnt, int* __restrict__ partial,
    int* __restrict__ bsum, int n) {
  __shared__ int s[256];
  int tid = threadIdx.x;
  int i = blockIdx.x * 256 + tid;
  s[tid] = (i < n) ? cnt[i] : 0;
  __syncthreads();
#pragma unroll
  for (int d = 1; d < 256; d <<= 1) {
    int t = (tid >= d) ? s[tid - d] : 0;
    __syncthreads();
    s[tid] += t;
    __syncthreads();
  }
  if (i < n) partial[i] = s[tid];
  if (tid == 255) bsum[blockIdx.x] = s[255];
}

__global__ __launch_bounds__(512) void k_scan_sums(int* __restrict__ bsum, int nb) {
  __shared__ int s[512];
  int tid = threadIdx.x;
  s[tid] = (tid < nb) ? bsum[tid] : 0;
  __syncthreads();
#pragma unroll
  for (int d = 1; d < 512; d <<= 1) {
    int t = (tid >= d) ? s[tid - d] : 0;
    __syncthreads();
    s[tid] += t;
    __syncthreads();
  }
  if (tid < nb) bsum[tid] = s[tid];
}

__global__ __launch_bounds__(256) void k_scan_add(
    const int* __restrict__ partial, const int* __restrict__ bsum,
    int* __restrict__ rowptr, int n) {
  int i = blockIdx.x * 256 + threadIdx.x;
  if (i == 0) rowptr[0] = 0;
  if (i < n) {
    int v = partial[i] + (blockIdx.x > 0 ? bsum[blockIdx.x - 1] : 0);
    rowptr[i + 1] = v;
  }
}

// fused: GRU#1 (blocks [0,nGru)) || csr fill (rest).
// GRU streams xh/h + MFMA; fill is NT scatter-write. No shared cache-
// sensitive state. GRU first in grid (longer).
__global__ __launch_bounds__(256, 3) void k_fill_gru(
    const unsigned short* __restrict__ xh, const float* h_in, float* h_out,
    const unsigned short* __restrict__ Bi, const unsigned short* __restrict__ Bh,
    const float* __restrict__ bih, const float* __restrict__ bhh, int M,
    const int* __restrict__ src, const int* __restrict__ dstI,
    const float* __restrict__ ew, const int* __restrict__ rowptr,
    const int* __restrict__ pos, int2* __restrict__ csr, int E, int nGru) {
  __shared__ unsigned char smem[2 * 24 * 1024];
  if ((int)blockIdx.x < nGru) {
    gru_body4(xh, h_in, h_out, Bi, Bh, bih, bhh, M, blockIdx.x, smem);
    return;
  }
  fill_body(src, dstI, ew, rowptr, pos, csr, E, blockIdx.x - nGru);
}

// fused: conv0 GEMM (blocks [0,nConv)) || deg/dinv (rest). conv first.
__global__ __launch_bounds__(256) void k_deg_conv(
    const unsigned short* __restrict__ A, const unsigned short* __restrict__ Bp,
    unsigned short* __restrict__ C, int M,
    const int* __restrict__ rowptr, const int2* __restrict__ csr,
    float* __restrict__ dinv, int N, int nConv) {
  __shared__ unsigned char smem[32 * 1024];
  if ((int)blockIdx.x < nConv) {
    gemm_body4<false, false, false>(A, Bp, nullptr, C, M, blockIdx.x, smem);
    return;
  }
  deg_body(rowptr, csr, dinv, N, blockIdx.x - nConv);
}

// in-place normalize: w = dinv[src] * ew_raw * dinv[dst] (512 thr)
__global__ __launch_bounds__(512) void k_norm(
    const int* __restrict__ rowptr, int2* __restrict__ csr,
    const float* __restrict__ dinv, int N) {
  int n = blockIdx.x * 512 + threadIdx.x;
  if (n >= N) return;
  int b = rowptr[n], e = rowptr[n + 1];
  float dn = dinv[n];
  for (int j = b; j < e; ++j) {
    unsigned long long v = __builtin_nontemporal_load((const unsigned long long*)(csr + j));
    int s = (int)v;
    float w = dinv[s] * __int_as_float((int)(v >> 32)) * dn;
    unsigned long long nv = (unsigned long long)(unsigned)s |
                            ((unsigned long long)(unsigned)__float_as_int(w) << 32);
    __builtin_nontemporal_store(nv, (unsigned long long*)(csr + j));
  }
}

// fused: GRU_l (blocks [0,nGru)) || conv_l GEMM (rest). Both read the same
// xh; GRU updates h in place, conv writes xw. GRU first (longer).
__global__ __launch_bounds__(256, 3) void k_gru_conv(
    const unsigned short* __restrict__ xh, const float* h_in, float* h_out,
    const unsigned short* __restrict__ Bi, const unsigned short* __restrict__ Bh,
    const float* __restrict__ bih, const float* __restrict__ bhh,
    const unsigned short* __restrict__ Bp, unsigned short* __restrict__ xw,
    int M, int nGru) {
  __shared__ unsigned char smem[2 * 24 * 1024];
  if ((int)blockIdx.x < nGru) {
    gru_body4(xh, h_in, h_out, Bi, Bh, bih, bhh, M, blockIdx.x, smem);
    return;
  }
  gemm_body4<false, false, false>(xh, Bp, nullptr, xw, M, blockIdx.x - nGru, smem);
}

// standalone GRU (final), 4 waves, dbuf staging
__global__ __launch_bounds__(256, 3) void k_gru(
    const unsigned short* __restrict__ xh, const float* h_in, float* h_out,
    const unsigned short* __restrict__ Bi, const unsigned short* __restrict__ Bh,
    const float* __restrict__ bih, const float* __restrict__ bhh, int M) {
  __shared__ unsigned char smem[2 * 24 * 1024];
  gru_body4(xh, h_in, h_out, Bi, Bh, bih, bhh, M, blockIdx.x, smem);
}

// ---------------------------------------------------------------------------
// CSR gather aggregation: 1 node per wave (max TLP), 4 waves/block (256 thr).
// NT loads on the streamed CSR; unroll-8 for ~8 outstanding random loads.
// ---------------------------------------------------------------------------

__global__ __launch_bounds__(256) void k_gather(
    const int* __restrict__ rowptr, const int2* __restrict__ csr,
    const unsigned* __restrict__ xw,   // [N,64] packed bf16x2
    const float* __restrict__ dinv, const float* __restrict__ bias,
    unsigned* __restrict__ out, int N) {
  int wave = threadIdx.x >> 6;
  int lane = threadIdx.x & 63;
  int node = __builtin_amdgcn_readfirstlane(blockIdx.x * 4 + wave);
  if (node >= N) return;
  int beg = __builtin_amdgcn_readfirstlane(rowptr[node]);
  int end = __builtin_amdgcn_readfirstlane(rowptr[node + 1]);

  float accl = 0.f, acch = 0.f;
  int k = beg;
  for (; k + 8 <= end; k += 8) {
    unsigned long long r0 = __builtin_nontemporal_load((const unsigned long long*)(csr + k));
    unsigned long long r1 = __builtin_nontemporal_load((const unsigned long long*)(csr + k + 1));
    unsigned long long r2 = __builtin_nontemporal_load((const unsigned long long*)(csr + k + 2));
    unsigned long long r3 = __builtin_nontemporal_load((const unsigned long long*)(csr + k + 3));
    unsigned long long r4 = __builtin_nontemporal_load((const unsigned long long*)(csr + k + 4));
    unsigned long long r5 = __builtin_nontemporal_load((const unsigned long long*)(csr + k + 5));
    unsigned long long r6 = __builtin_nontemporal_load((const unsigned long long*)(csr + k + 6));
    unsigned long long r7 = __builtin_nontemporal_load((const unsigned long long*)(csr + k + 7));
    unsigned v0 = xw[((size_t)(unsigned)r0 << 6) + lane];
    unsigned v1 = xw[((size_t)(unsigned)r1 << 6) + lane];
    unsigned v2 = xw[((size_t)(unsigned)r2 << 6) + lane];
    unsigned v3 = xw[((size_t)(unsigned)r3 << 6) + lane];
    unsigned v4 = xw[((size_t)(unsigned)r4 << 6) + lane];
    unsigned v5 = xw[((size_t)(unsigned)r5 << 6) + lane];
    unsigned v6 = xw[((size_t)(unsigned)r6 << 6) + lane];
    unsigned v7 = xw[((size_t)(unsigned)r7 << 6) + lane];
    float w0 = __int_as_float((int)(r0 >> 32)), w1 = __int_as_float((int)(r1 >> 32));
    float w2 = __int_as_float((int)(r2 >> 32)), w3 = __int_as_float((int)(r3 >> 32));
    float w4 = __int_as_float((int)(r4 >> 32)), w5 = __int_as_float((int)(r5 >> 32));
    float w6 = __int_as_float((int)(r6 >> 32)), w7 = __int_as_float((int)(r7 >> 32));
    accl += bflo(v0) * w0; acch += bfhi(v0) * w0;
    accl += bflo(v1) * w1; acch += bfhi(v1) * w1;
    accl += bflo(v2) * w2; acch += bfhi(v2) * w2;
    accl += bflo(v3) * w3; acch += bfhi(v3) * w3;
    accl += bflo(v4) * w4; acch += bfhi(v4) * w4;
    accl += bflo(v5) * w5; acch += bfhi(v5) * w5;
    accl += bflo(v6) * w6; acch += bfhi(v6) * w6;
    accl += bflo(v7) * w7; acch += bfhi(v7) * w7;
  }
  for (; k + 4 <= end; k += 4) {
    unsigned long long r0 = __builtin_nontemporal_load((const unsigned long long*)(csr + k));
    unsigned long long r1 = __builtin_nontemporal_load((const unsigned long long*)(csr + k + 1));
    unsigned long long r2 = __builtin_nontemporal_load((const unsigned long long*)(csr + k + 2));
    unsigned long long r3 = __builtin_nontemporal_load((const unsigned long long*)(csr + k + 3));
    unsigned v0 = xw[((size_t)(unsigned)r0 << 6) + lane];
    unsigned v1 = xw[((size_t)(unsigned)r1 << 6) + lane];
    unsigned v2 = xw[((size_t)(unsigned)r2 << 6) + lane];
    unsigned v3 = xw[((size_t)(unsigned)r3 << 6) + lane];
    float w0 = __int_as_float((int)(r0 >> 32)), w1 = __int_as_float((int)(r1 >> 32));
    float w2 = __int_as_float((int)(r2 >> 32)), w3 = __int_as_float((int)(r3 >> 32));
    accl += bflo(v0) * w0; acch += bfhi(v0) * w0;
    accl += bflo(v1) * w1; acch += bfhi(v1) * w1;
    accl += bflo(v2) * w2; acch += bfhi(v2) * w2;
    accl += bflo(v3) * w3; acch += bfhi(v3) * w3;
  }
  for (; k < end; ++k) {
    unsigned long long r = __builtin_nontemporal_load((const unsigned long long*)(csr + k));
    unsigned v = xw[((size_t)(unsigned)r << 6) + lane];
    float w = __int_as_float((int)(r >> 32));
    accl += bflo(v) * w; acch += bfhi(v) * w;
  }

  float di = dinv[node];
  float sn = di * di;
  unsigned vs = xw[((size_t)node << 6) + lane];
  float2 b = *(const float2*)(bias + lane * 2);
  float rl = fmaxf(accl + bflo(vs) * sn + b.x, 0.f);
  float rh = fmaxf(acch + bfhi(vs) * sn + b.y, 0.f);
  unsigned o = (unsigned)f2bf(rl) | ((unsigned)f2bf(rh) << 16);
  out[((size_t)node << 6) + lane] = o;
}

// ---------------------------------------------------------------------------
// fp32 GEMM (final fc layer)
// ---------------------------------------------------------------------------

template<bool RELU, bool BIAS>
__global__ __launch_bounds__(256) void k_gemm128(
    const float* __restrict__ A, const float* __restrict__ B,
    const float* __restrict__ bias, float* __restrict__ C, int M, int Nc) {
  __shared__ float As[64][36];
  __shared__ float Bs[32][64];
  int tid = threadIdx.x;
  int tx = tid & 15, ty = tid >> 4;
  int row0 = blockIdx.y * 64, col0 = blockIdx.x * 64;
  float acc[4][4] = {};

  for (int k0 = 0; k0 < 128; k0 += 32) {
#pragma unroll
    for (int i = 0; i < 2; ++i) {
      int f = tid + i * 256;
      int r = f >> 3, c4 = f & 7;
      int gr = row0 + r;
      float4 v = make_float4(0.f, 0.f, 0.f, 0.f);
      if (gr < M) v = *(const float4*)(A + (size_t)gr * 128 + k0 + c4 * 4);
      *(float4*)(&As[r][c4 * 4]) = v;
    }
#pragma unroll
    for (int i = 0; i < 2; ++i) {
      int f = tid + i * 256;
      int r = f >> 4, c4 = f & 15;
      int gc = col0 + c4 * 4;
      float4 v = make_float4(0.f, 0.f, 0.f, 0.f);
      if (gc + 3 < Nc) v = *(const float4*)(B + (size_t)(k0 + r) * Nc + gc);
      *(float4*)(&Bs[r][c4 * 4]) = v;
    }
    __syncthreads();
#pragma unroll
    for (int kk = 0; kk < 32; ++kk) {
      float4 b = *(float4*)(&Bs[kk][tx * 4]);
      float a0 = As[ty * 4 + 0][kk];
      float a1 = As[ty * 4 + 1][kk];
      float a2 = As[ty * 4 + 2][kk];
      float a3 = As[ty * 4 + 3][kk];
      acc[0][0] += a0 * b.x; acc[0][1] += a0 * b.y; acc[0][2] += a0 * b.z; acc[0][3] += a0 * b.w;
      acc[1][0] += a1 * b.x; acc[1][1] += a1 * b.y; acc[1][2] += a1 * b.z; acc[1][3] += a1 * b.w;
      acc[2][0] += a2 * b.x; acc[2][1] += a2 * b.y; acc[2][2] += a2 * b.z; acc[2][3] += a2 * b.w;
      acc[3][0] += a3 * b.x; acc[3][1] += a3 * b.y; acc[3][2] += a3 * b.z; acc[3][3] += a3 * b.w;
    }
    __syncthreads();
  }

#pragma unroll
  for (int i = 0; i < 4; ++i) {
    int gr = row0 + ty * 4 + i;
    if (gr >= M) continue;
#pragma unroll
    for (int j = 0; j < 4; ++j) {
      int gc = col0 + tx * 4 + j;
      if (gc >= Nc) continue;
      float v = acc[i][j];
      if (BIAS) v += bias[gc];
      if (RELU) v = fmaxf(v, 0.f);
      C[(size_t)gr * Nc + gc] = v;
    }
  }
}

// ---------------------------------------------------------------------------

extern "C" void kernel_launch(void* const* d_in, const int* in_sizes, int n_in,
                              void* d_out, int out_size, void* d_ws, size_t ws_size,
                              hipStream_t stream) {
  const float* x    = (const float*)d_in[0];
  const int*   ei   = (const int*)d_in[1];
  const float* ew   = (const float*)d_in[2];
  const float* h0   = (const float*)d_in[3];
  const float* linW = (const float*)d_in[4];
  const float* linB = (const float*)d_in[5];
  const float* convW= (const float*)d_in[6];
  const float* convB= (const float*)d_in[7];
  const float* Wih  = (const float*)d_in[8];
  const float* Whh  = (const float*)d_in[9];
  const float* bih  = (const float*)d_in[10];
  const float* bhh  = (const float*)d_in[11];
  const float* fcW  = (const float*)d_in[12];
  const float* fcB  = (const float*)d_in[13];

  int N = in_sizes[0] / 128;
  int E = in_sizes[1] / 2;
  const int* srcI = ei;
  const int* dstI = ei + E;
  int nb = (N + 255) / 256;

  // ---- workspace layout ----
  float* ws = (float*)d_ws;
  size_t off = 0;
  float* dinv = ws + off; off += (size_t)N;
  if (off & 1) off++;                       // 8B-align what follows
  float* h    = ws + off; off += (size_t)N * 128;
  int* iws = (int*)(ws + off);              // 8B-aligned
  size_t ioff = 0;
  int2* csr    = (int2*)iws; ioff += (size_t)2 * E;
  int* cnt     = iws + ioff; ioff += (size_t)N;
  int* partial = iws + ioff; ioff += (size_t)N;
  int* bsum    = iws + ioff; ioff += 512;
  int* rowptr  = iws + ioff; ioff += (size_t)N + 1;
  ioff = (ioff + 3) & ~(size_t)3;           // 16B-align ushort area
  unsigned short* usws = (unsigned short*)(iws + ioff);
  size_t uoff = 0;
  unsigned short* xh_bf  = usws + uoff; uoff += (size_t)N * 128;
  unsigned short* xw_bf  = usws + uoff; uoff += (size_t)N * 128;
  unsigned short* linWp  = usws + uoff; uoff += 128 * 128;
  unsigned short* convWp = usws + uoff; uoff += 3 * 128 * 128;
  unsigned short* Bi     = usws + uoff; uoff += 384 * 128;
  unsigned short* Bh     = usws + uoff; uoff += 384 * 128;

  // pos[E] aliases xw_bf (pos dies at k_fill_gru; xw first written by conv0
  // inside k_deg_conv, a later dispatch)
  int* pos = (int*)xw_bf;

  int gw4  = (N + 63) / 64;         // 4 waves x 16 rows per block
  int nCnt = (E + 255) / 256;
  int n512 = (N + 511) / 512;
  int e512 = (E + 511) / 512;
  int ggat = (N + 3) / 4;           // 1 node/wave, 4 waves/block

  // 1) packs + zero cnt
  k_prep<<<80 + nb, 256, 0, stream>>>(linW, convW, Wih, Whh,
                                      linWp, convWp, Bi, Bh, cnt, N);
  // 2) count+pos || xh = relu(x@linW + linB)
  k_count_lin<<<nCnt + gw4, 256, 0, stream>>>(dstI, cnt, pos, E,
                                              x, linWp, linB, xh_bf, N, nCnt);
  // 3-5) rowptr scan
  k_scan_block<<<nb, 256, 0, stream>>>(cnt, partial, bsum, N);
  k_scan_sums<<<1, 512, 0, stream>>>(bsum, nb);
  k_scan_add<<<nb, 256, 0, stream>>>(partial, bsum, rowptr, N);
  // 6) GRU#1 (h0 -> h) || csr fill
  k_fill_gru<<<gw4 + e512, 256, 0, stream>>>(
      xh_bf, h0, h, Bi, Bh, bih, bhh, N,
      srcI, dstI, ew, rowptr, pos, csr, E, gw4);
  // 7) conv0 (xh -> xw) || deg/dinv
  k_deg_conv<<<gw4 + n512, 256, 0, stream>>>(
      xh_bf, convWp, xw_bf, N, rowptr, csr, dinv, N, gw4);
  // 8) normalize csr weights
  k_norm<<<n512, 512, 0, stream>>>(rowptr, csr, dinv, N);
  // 9+) per layer: gather_l, then {GRU_{l+1} || conv_{l+1}} (last: GRU only)
  for (int l = 0; l < 3; ++l) {
    k_gather<<<ggat, 256, 0, stream>>>(
        rowptr, csr, (const unsigned*)xw_bf, dinv, convB + (size_t)l * 128,
        (unsigned*)xh_bf, N);
    if (l < 2) {
      k_gru_conv<<<2 * gw4, 256, 0, stream>>>(
          xh_bf, h, h, Bi, Bh, bih, bhh,
          convWp + (size_t)(l + 1) * 128 * 128, xw_bf, N, gw4);
    } else {
      k_gru<<<gw4, 256, 0, stream>>>(xh_bf, h, h, Bi, Bh, bih, bhh, N);
    }
  }
  // out = h @ fcW + fcB (fp32)
  dim3 g40(1, (N + 63) / 64);
  k_gemm128<false, true><<<g40, 256, 0, stream>>>(h, fcW, fcB, (float*)d_out, N, 40);
}

// Round 9
// 868.518 us; speedup vs baseline: 1.1902x; 1.1902x over previous
//
#include <hip/hip_runtime.h>
#include <hip/hip_bf16.h>
#include <math.h>

typedef __attribute__((ext_vector_type(8))) short bf8_t;   // 8 x bf16 (4 VGPRs)
typedef __attribute__((ext_vector_type(4))) float f4_t;    // MFMA accumulator
typedef __attribute__((ext_vector_type(8))) unsigned short us8_t;

__device__ inline unsigned short f2bf(float f) {
  union { float f; unsigned u; } x; x.f = f;
  unsigned r = x.u + 0x7FFF + ((x.u >> 16) & 1);   // RNE
  return (unsigned short)(r >> 16);
}
__device__ inline float bflo(unsigned v) {
  union { unsigned u; float f; } x; x.u = v << 16; return x.f;
}
__device__ inline float bfhi(unsigned v) {
  union { unsigned u; float f; } x; x.u = v & 0xFFFF0000u; return x.f;
}
__device__ inline float fast_sig(float x) {
  return __builtin_amdgcn_rcpf(1.f + __expf(-x));
}
__device__ inline float fast_tanh(float x) {
  return 1.f - 2.f * __builtin_amdgcn_rcpf(1.f + __expf(2.f * x));
}

// async global->LDS copy, 16B per lane; LDS dest = base + lane*16 (HW rule)
__device__ inline void async_copy16(const void* g, void* l) {
  __builtin_amdgcn_global_load_lds(
      (const __attribute__((address_space(1))) unsigned int*)g,
      (__attribute__((address_space(3))) unsigned int*)l, 16, 0, 0);
}

__device__ inline bf8_t pack_bf8(const float* p) {
  float4 a = *(const float4*)p;
  float4 b = *(const float4*)(p + 4);
  bf8_t t;
  t[0] = (short)f2bf(a.x); t[1] = (short)f2bf(a.y);
  t[2] = (short)f2bf(a.z); t[3] = (short)f2bf(a.w);
  t[4] = (short)f2bf(b.x); t[5] = (short)f2bf(b.y);
  t[6] = (short)f2bf(b.z); t[7] = (short)f2bf(b.w);
  return t;
}

// ---------------------------------------------------------------------------
// device bodies
// ---------------------------------------------------------------------------

// pack weight matrix into MFMA B-fragment order (16x16x32 bf16).
__device__ inline void packB_body(const float* __restrict__ W,
                                  unsigned short* __restrict__ out,
                                  int K, int Ncols, int ldw, int trans, int bid) {
  int idx = bid * 256 + threadIdx.x;
  int total = (Ncols / 16) * (K / 32) * 64;
  if (idx >= total) return;
  int lane = idx & 63;
  int frag = idx >> 6;
  int kt = K / 32;
  int k0 = frag % kt;
  int n0 = frag / kt;
  int n = n0 * 16 + (lane & 15);
  int kbase = k0 * 32 + (lane >> 4) * 8;
  us8_t v;
#pragma unroll
  for (int j = 0; j < 8; ++j) {
    int k = kbase + j;
    float f = trans ? W[(size_t)n * ldw + k] : W[(size_t)k * ldw + n];
    v[j] = f2bf(f);
  }
  *(us8_t*)(out + (size_t)idx * 8) = v;
}

// MFMA GEMM body, 4 waves x 16 rows = 64 rows/block; 32KB smem.
// F32A: A is fp32, converted to bf16 in-register at load.
template<bool RELU, bool BIAS, bool F32A>
__device__ inline void gemm_body4(const void* __restrict__ Araw,
                                  const unsigned short* __restrict__ Bp,
                                  const float* __restrict__ bias,
                                  unsigned short* __restrict__ C, int M, int bid,
                                  unsigned char* smem) {
  int wave = threadIdx.x >> 6, lane = threadIdx.x & 63;
  int row0 = (bid * 4 + wave) * 16;
  int m = lane & 15, q = lane >> 4;

#pragma unroll
  for (int i = 0; i < 8; ++i) {
    int f = wave * 8 + i;
    async_copy16((const unsigned char*)Bp + (size_t)f * 1024 + lane * 16,
                 smem + f * 1024);
  }
  __syncthreads();
  if (row0 >= M) return;

  int arow = row0 + m; if (arow >= M) arow = M - 1;
  bf8_t a[4];
#pragma unroll
  for (int k0 = 0; k0 < 4; ++k0) {
    if (F32A) {
      a[k0] = pack_bf8((const float*)Araw + (size_t)arow * 128 + k0 * 32 + q * 8);
    } else {
      a[k0] = *(const bf8_t*)((const unsigned short*)Araw +
                              (size_t)arow * 128 + k0 * 32 + q * 8);
    }
  }

#pragma unroll
  for (int n0 = 0; n0 < 8; ++n0) {
    f4_t acc = {};
#pragma unroll
    for (int k0 = 0; k0 < 4; ++k0) {
      bf8_t b = *(const bf8_t*)(smem + (n0 * 4 + k0) * 1024 + lane * 16);
      acc = __builtin_amdgcn_mfma_f32_16x16x32_bf16(a[k0], b, acc, 0, 0, 0);
    }
    int col = n0 * 16 + m;
    float bs = BIAS ? bias[col] : 0.f;
#pragma unroll
    for (int r = 0; r < 4; ++r) {
      int grow = row0 + q * 4 + r;
      if (grow < M) {
        float v = acc[r] + bs;
        if (RELU) v = fmaxf(v, 0.f);
        C[(size_t)grow * 128 + col] = f2bf(v);
      }
    }
  }
}

// GRU B-staging, 4 waves: wave stages 6 of 24 frags into one 24KB half
__device__ inline void gru_stage4(const unsigned short* __restrict__ Bi,
                                  const unsigned short* __restrict__ Bh,
                                  unsigned char* half, int wave, int lane, int g) {
#pragma unroll
  for (int s = 0; s < 6; ++s) {
    int cc = g + 8 * (s >= 3 ? s - 3 : s);
    const unsigned short* src = (s < 3) ? Bi : Bh;
    int f = s * 4 + wave;
    async_copy16((const unsigned char*)src + ((size_t)(cc * 4 + wave)) * 1024 + lane * 16,
                 half + f * 1024);
  }
}

// GRU core, 4 waves, DOUBLE-BUFFERED staging (smem = 2 x 24KB).
// In-place h safe; fully unrolled (static indices, no scratch).
__device__ inline void gru_core4(const bf8_t* ax, const float* h_in, float* h_out,
                                 const unsigned short* __restrict__ Bi,
                                 const unsigned short* __restrict__ Bh,
                                 const float* __restrict__ bih, const float* __restrict__ bhh,
                                 int M, int row0, int wave, int lane,
                                 unsigned char* smem) {
  int m = lane & 15, q = lane >> 4;
  int arow = row0 + m; if (arow >= M) arow = M - 1;

  bf8_t ah[4];
#pragma unroll
  for (int k0 = 0; k0 < 4; ++k0)
    ah[k0] = pack_bf8(h_in + (size_t)arow * 128 + k0 * 32 + q * 8);

  int erow[4];
#pragma unroll
  for (int r = 0; r < 4; ++r) {
    int gr = row0 + q * 4 + r;
    erow[r] = (gr < M) ? gr : (M - 1);
  }

  float hp_cur[4], hp_nxt[4];
#pragma unroll
  for (int r = 0; r < 4; ++r)
    hp_cur[r] = h_in[(size_t)erow[r] * 128 + m];

#pragma unroll
  for (int g = 0; g < 8; ++g) {
    __syncthreads();   // stage(g) complete; prev group's LDS reads all done
    if (g < 7)         // issue next stage NOW -> hides under MFMA + epilogue
      gru_stage4(Bi, Bh, smem + ((g + 1) & 1) * (24 * 1024), wave, lane, g + 1);
    unsigned char* cur = smem + (g & 1) * (24 * 1024);

    f4_t air = {}, aiz = {}, ain = {}, ahr = {}, ahz = {}, ahn = {};
#pragma unroll
    for (int k0 = 0; k0 < 4; ++k0) {
      bf8_t br = *(const bf8_t*)(cur + (0 * 4 + k0) * 1024 + lane * 16);
      bf8_t bz = *(const bf8_t*)(cur + (1 * 4 + k0) * 1024 + lane * 16);
      bf8_t bn = *(const bf8_t*)(cur + (2 * 4 + k0) * 1024 + lane * 16);
      bf8_t cr = *(const bf8_t*)(cur + (3 * 4 + k0) * 1024 + lane * 16);
      bf8_t cz = *(const bf8_t*)(cur + (4 * 4 + k0) * 1024 + lane * 16);
      bf8_t cn = *(const bf8_t*)(cur + (5 * 4 + k0) * 1024 + lane * 16);
      air = __builtin_amdgcn_mfma_f32_16x16x32_bf16(ax[k0], br, air, 0, 0, 0);
      aiz = __builtin_amdgcn_mfma_f32_16x16x32_bf16(ax[k0], bz, aiz, 0, 0, 0);
      ain = __builtin_amdgcn_mfma_f32_16x16x32_bf16(ax[k0], bn, ain, 0, 0, 0);
      ahr = __builtin_amdgcn_mfma_f32_16x16x32_bf16(ah[k0], cr, ahr, 0, 0, 0);
      ahz = __builtin_amdgcn_mfma_f32_16x16x32_bf16(ah[k0], cz, ahz, 0, 0, 0);
      ahn = __builtin_amdgcn_mfma_f32_16x16x32_bf16(ah[k0], cn, ahn, 0, 0, 0);
    }
    if (g < 7) {                         // issue next group's hprev loads
#pragma unroll
      for (int r = 0; r < 4; ++r)
        hp_nxt[r] = h_in[(size_t)erow[r] * 128 + (g + 1) * 16 + m];
    }

    int col = g * 16 + m;
    float bir_ = bih[col], biz_ = bih[col + 128], bin_ = bih[col + 256];
    float bhr_ = bhh[col], bhz_ = bhh[col + 128], bhn_ = bhh[col + 256];
#pragma unroll
    for (int r = 0; r < 4; ++r) {
      int grow = row0 + q * 4 + r;
      if (grow < M) {
        float rr = fast_sig(air[r] + bir_ + ahr[r] + bhr_);
        float zz = fast_sig(aiz[r] + biz_ + ahz[r] + bhz_);
        float nn = fast_tanh(ain[r] + bin_ + rr * (ahn[r] + bhn_));
        h_out[(size_t)grow * 128 + col] = (1.f - zz) * nn + zz * hp_cur[r];
      }
    }
#pragma unroll
    for (int r = 0; r < 4; ++r) hp_cur[r] = hp_nxt[r];
  }
}

// ---------------------------------------------------------------------------
// kernels (R7-888 structure: only count||lin fused; everything else
// standalone. R2/R5/R8 lessons: no serializing fusion, no cache-sensitive
// gather pairing, no footprint-union fusion.)
// ---------------------------------------------------------------------------

// prep: all 6 weight packs + zero cnt, one launch (256 thr)
__global__ __launch_bounds__(256) void k_prep(
    const float* __restrict__ linW, const float* __restrict__ convW,
    const float* __restrict__ Wih, const float* __restrict__ Whh,
    unsigned short* __restrict__ linWp, unsigned short* __restrict__ convWp,
    unsigned short* __restrict__ Bi, unsigned short* __restrict__ Bh,
    int* __restrict__ cnt, int N) {
  int b = blockIdx.x;
  if (b < 8)  { packB_body(linW, linWp, 128, 128, 128, 0, b); return; }
  if (b < 32) { int l = (b - 8) >> 3;
                packB_body(convW + (size_t)l * 16384, convWp + (size_t)l * 16384,
                           128, 128, 128, 0, (b - 8) & 7); return; }
  if (b < 56) { packB_body(Wih, Bi, 128, 384, 128, 1, b - 32); return; }
  if (b < 80) { packB_body(Whh, Bh, 128, 384, 128, 1, b - 56); return; }
  int i = (b - 80) * 256 + threadIdx.x;
  if (i < N) cnt[i] = 0;
}

// fused: atomic histogram+pos (blocks [0,nCnt)) || lin GEMM from fp32 x
__global__ __launch_bounds__(256) void k_count_lin(
    const int* __restrict__ dst, int* __restrict__ cnt, int* __restrict__ pos, int E,
    const float* __restrict__ x, const unsigned short* __restrict__ linWp,
    const float* __restrict__ linB, unsigned short* __restrict__ xh, int M,
    int nCnt) {
  __shared__ unsigned char smem[32 * 1024];
  if ((int)blockIdx.x < nCnt) {
    int e = blockIdx.x * 256 + threadIdx.x;
    if (e < E) pos[e] = atomicAdd(&cnt[dst[e]], 1);
    return;
  }
  gemm_body4<true, true, true>(x, linWp, linB, xh, M, blockIdx.x - nCnt, smem);
}

// hierarchical scan for rowptr
__global__ __launch_bounds__(256) void k_scan_block(
    const int* __restrict__ cnt, int* __restrict__ partial,
    int* __restrict__ bsum, int n) {
  __shared__ int s[256];
  int tid = threadIdx.x;
  int i = blockIdx.x * 256 + tid;
  s[tid] = (i < n) ? cnt[i] : 0;
  __syncthreads();
#pragma unroll
  for (int d = 1; d < 256; d <<= 1) {
    int t = (tid >= d) ? s[tid - d] : 0;
    __syncthreads();
    s[tid] += t;
    __syncthreads();
  }
  if (i < n) partial[i] = s[tid];
  if (tid == 255) bsum[blockIdx.x] = s[255];
}

// scan_add with block-local bsum scan (merges old scan_sums dispatch).
// Each block redundantly scans up to 512 bsums in LDS.
__global__ __launch_bounds__(256) void k_scan_add(
    const int* __restrict__ partial, const int* __restrict__ bsum,
    int* __restrict__ rowptr, int n, int nb) {
  __shared__ int s[512];
  int tid = threadIdx.x;
  s[tid] = (tid < nb) ? bsum[tid] : 0;
  s[tid + 256] = (tid + 256 < nb) ? bsum[tid + 256] : 0;
  __syncthreads();
#pragma unroll
  for (int d = 1; d < 512; d <<= 1) {
    int t0 = (tid >= d) ? s[tid - d] : 0;
    int t1 = (tid + 256 >= d) ? s[tid + 256 - d] : 0;
    __syncthreads();
    s[tid] += t0;
    s[tid + 256] += t1;
    __syncthreads();
  }
  int base = (blockIdx.x > 0) ? s[blockIdx.x - 1] : 0;
  int i = blockIdx.x * 256 + tid;
  if (i == 0) rowptr[0] = 0;
  if (i < n) rowptr[i + 1] = partial[i] + base;
}

// atomic-free CSR fill (slot from pos[]), RAW weight, NT store (512 thr)
__global__ __launch_bounds__(512) void k_fill(
    const int* __restrict__ src, const int* __restrict__ dst,
    const float* __restrict__ ew, const int* __restrict__ rowptr,
    const int* __restrict__ pos, int2* __restrict__ csr, int E) {
  int e = blockIdx.x * 512 + threadIdx.x;
  if (e >= E) return;
  int d = dst[e];
  int p = rowptr[d] + pos[e];
  unsigned long long v = (unsigned long long)(unsigned)src[e] |
                         ((unsigned long long)(unsigned)__float_as_int(ew[e]) << 32);
  __builtin_nontemporal_store(v, (unsigned long long*)(csr + p));
}

// deg[n] = 1 + sum raw incoming ew; dinv = rsqrt (512 thr)
__global__ __launch_bounds__(512) void k_deg(
    const int* __restrict__ rowptr, const int2* __restrict__ csr,
    float* __restrict__ dinv, int N) {
  int n = blockIdx.x * 512 + threadIdx.x;
  if (n >= N) return;
  int b = rowptr[n], e = rowptr[n + 1];
  float s = 1.0f;
  for (int j = b; j < e; ++j) {
    unsigned long long v = __builtin_nontemporal_load((const unsigned long long*)(csr + j));
    s += __int_as_float((int)(v >> 32));
  }
  dinv[n] = rsqrtf(s);
}

// conv GEMM (bf16 A), 4 waves / 256 thr
__global__ __launch_bounds__(256) void k_conv(
    const unsigned short* __restrict__ A, const unsigned short* __restrict__ Bp,
    unsigned short* __restrict__ C, int M) {
  __shared__ unsigned char smem[32 * 1024];
  gemm_body4<false, false, false>(A, Bp, nullptr, C, M, blockIdx.x, smem);
}

// GRU, 4 waves / 256 thr, double-buffered staging (48KB -> 3 blocks/CU)
__global__ __launch_bounds__(256, 3) void k_gru(
    const unsigned short* __restrict__ xh, const float* h_in, float* h_out,
    const unsigned short* __restrict__ Bi, const unsigned short* __restrict__ Bh,
    const float* __restrict__ bih, const float* __restrict__ bhh, int M) {
  __shared__ unsigned char smem[2 * 24 * 1024];
  int wave = threadIdx.x >> 6, lane = threadIdx.x & 63;
  int row0 = (blockIdx.x * 4 + wave) * 16;
  gru_stage4(Bi, Bh, smem, wave, lane, 0);
  int m = lane & 15, q = lane >> 4;
  int arow = row0 + m; if (arow >= M) arow = M - 1;
  bf8_t ax[4];
#pragma unroll
  for (int k0 = 0; k0 < 4; ++k0)
    ax[k0] = *(const bf8_t*)(xh + (size_t)arow * 128 + k0 * 32 + q * 8);
  gru_core4(ax, h_in, h_out, Bi, Bh, bih, bhh, M, row0, wave, lane, smem);
}

// ---------------------------------------------------------------------------
// CSR gather aggregation: 1 node per wave (max TLP), 4 waves/block (256 thr).
// CSR holds RAW ew; normalization dinv[src]*ew*dinv[dst] computed inline
// (dinv is 400KB -> L2-resident; uniform 4B load per edge, same product
// order as the old k_norm pass -> bit-identical numerics).
// ---------------------------------------------------------------------------

__global__ __launch_bounds__(256) void k_gather(
    const int* __restrict__ rowptr, const int2* __restrict__ csr,
    const unsigned* __restrict__ xw,   // [N,64] packed bf16x2
    const float* __restrict__ dinv, const float* __restrict__ bias,
    unsigned* __restrict__ out, int N) {
  int wave = threadIdx.x >> 6;
  int lane = threadIdx.x & 63;
  int node = __builtin_amdgcn_readfirstlane(blockIdx.x * 4 + wave);
  if (node >= N) return;
  int beg = __builtin_amdgcn_readfirstlane(rowptr[node]);
  int end = __builtin_amdgcn_readfirstlane(rowptr[node + 1]);
  float di = dinv[node];

  float accl = 0.f, acch = 0.f;
  int k = beg;
  for (; k + 4 <= end; k += 4) {
    unsigned long long r0 = __builtin_nontemporal_load((const unsigned long long*)(csr + k));
    unsigned long long r1 = __builtin_nontemporal_load((const unsigned long long*)(csr + k + 1));
    unsigned long long r2 = __builtin_nontemporal_load((const unsigned long long*)(csr + k + 2));
    unsigned long long r3 = __builtin_nontemporal_load((const unsigned long long*)(csr + k + 3));
    unsigned v0 = xw[((size_t)(unsigned)r0 << 6) + lane];
    unsigned v1 = xw[((size_t)(unsigned)r1 << 6) + lane];
    unsigned v2 = xw[((size_t)(unsigned)r2 << 6) + lane];
    unsigned v3 = xw[((size_t)(unsigned)r3 << 6) + lane];
    float w0 = dinv[(unsigned)r0] * __int_as_float((int)(r0 >> 32)) * di;
    float w1 = dinv[(unsigned)r1] * __int_as_float((int)(r1 >> 32)) * di;
    float w2 = dinv[(unsigned)r2] * __int_as_float((int)(r2 >> 32)) * di;
    float w3 = dinv[(unsigned)r3] * __int_as_float((int)(r3 >> 32)) * di;
    accl += bflo(v0) * w0; acch += bfhi(v0) * w0;
    accl += bflo(v1) * w1; acch += bfhi(v1) * w1;
    accl += bflo(v2) * w2; acch += bfhi(v2) * w2;
    accl += bflo(v3) * w3; acch += bfhi(v3) * w3;
  }
  for (; k < end; ++k) {
    unsigned long long r = __builtin_nontemporal_load((const unsigned long long*)(csr + k));
    unsigned v = xw[((size_t)(unsigned)r << 6) + lane];
    float w = dinv[(unsigned)r] * __int_as_float((int)(r >> 32)) * di;
    accl += bflo(v) * w; acch += bfhi(v) * w;
  }

  float sn = di * di;
  unsigned vs = xw[((size_t)node << 6) + lane];
  float2 b = *(const float2*)(bias + lane * 2);
  float rl = fmaxf(accl + bflo(vs) * sn + b.x, 0.f);
  float rh = fmaxf(acch + bfhi(vs) * sn + b.y, 0.f);
  unsigned o = (unsigned)f2bf(rl) | ((unsigned)f2bf(rh) << 16);
  out[((size_t)node << 6) + lane] = o;
}

// ---------------------------------------------------------------------------
// fp32 GEMM (final fc layer)
// ---------------------------------------------------------------------------

template<bool RELU, bool BIAS>
__global__ __launch_bounds__(256) void k_gemm128(
    const float* __restrict__ A, const float* __restrict__ B,
    const float* __restrict__ bias, float* __restrict__ C, int M, int Nc) {
  __shared__ float As[64][36];
  __shared__ float Bs[32][64];
  int tid = threadIdx.x;
  int tx = tid & 15, ty = tid >> 4;
  int row0 = blockIdx.y * 64, col0 = blockIdx.x * 64;
  float acc[4][4] = {};

  for (int k0 = 0; k0 < 128; k0 += 32) {
#pragma unroll
    for (int i = 0; i < 2; ++i) {
      int f = tid + i * 256;
      int r = f >> 3, c4 = f & 7;
      int gr = row0 + r;
      float4 v = make_float4(0.f, 0.f, 0.f, 0.f);
      if (gr < M) v = *(const float4*)(A + (size_t)gr * 128 + k0 + c4 * 4);
      *(float4*)(&As[r][c4 * 4]) = v;
    }
#pragma unroll
    for (int i = 0; i < 2; ++i) {
      int f = tid + i * 256;
      int r = f >> 4, c4 = f & 15;
      int gc = col0 + c4 * 4;
      float4 v = make_float4(0.f, 0.f, 0.f, 0.f);
      if (gc + 3 < Nc) v = *(const float4*)(B + (size_t)(k0 + r) * Nc + gc);
      *(float4*)(&Bs[r][c4 * 4]) = v;
    }
    __syncthreads();
#pragma unroll
    for (int kk = 0; kk < 32; ++kk) {
      float4 b = *(float4*)(&Bs[kk][tx * 4]);
      float a0 = As[ty * 4 + 0][kk];
      float a1 = As[ty * 4 + 1][kk];
      float a2 = As[ty * 4 + 2][kk];
      float a3 = As[ty * 4 + 3][kk];
      acc[0][0] += a0 * b.x; acc[0][1] += a0 * b.y; acc[0][2] += a0 * b.z; acc[0][3] += a0 * b.w;
      acc[1][0] += a1 * b.x; acc[1][1] += a1 * b.y; acc[1][2] += a1 * b.z; acc[1][3] += a1 * b.w;
      acc[2][0] += a2 * b.x; acc[2][1] += a2 * b.y; acc[2][2] += a2 * b.z; acc[2][3] += a2 * b.w;
      acc[3][0] += a3 * b.x; acc[3][1] += a3 * b.y; acc[3][2] += a3 * b.z; acc[3][3] += a3 * b.w;
    }
    __syncthreads();
  }

#pragma unroll
  for (int i = 0; i < 4; ++i) {
    int gr = row0 + ty * 4 + i;
    if (gr >= M) continue;
#pragma unroll
    for (int j = 0; j < 4; ++j) {
      int gc = col0 + tx * 4 + j;
      if (gc >= Nc) continue;
      float v = acc[i][j];
      if (BIAS) v += bias[gc];
      if (RELU) v = fmaxf(v, 0.f);
      C[(size_t)gr * Nc + gc] = v;
    }
  }
}

// ---------------------------------------------------------------------------

extern "C" void kernel_launch(void* const* d_in, const int* in_sizes, int n_in,
                              void* d_out, int out_size, void* d_ws, size_t ws_size,
                              hipStream_t stream) {
  const float* x    = (const float*)d_in[0];
  const int*   ei   = (const int*)d_in[1];
  const float* ew   = (const float*)d_in[2];
  const float* h0   = (const float*)d_in[3];
  const float* linW = (const float*)d_in[4];
  const float* linB = (const float*)d_in[5];
  const float* convW= (const float*)d_in[6];
  const float* convB= (const float*)d_in[7];
  const float* Wih  = (const float*)d_in[8];
  const float* Whh  = (const float*)d_in[9];
  const float* bih  = (const float*)d_in[10];
  const float* bhh  = (const float*)d_in[11];
  const float* fcW  = (const float*)d_in[12];
  const float* fcB  = (const float*)d_in[13];

  int N = in_sizes[0] / 128;
  int E = in_sizes[1] / 2;
  const int* srcI = ei;
  const int* dstI = ei + E;
  int nb = (N + 255) / 256;

  // ---- workspace layout ----
  float* ws = (float*)d_ws;
  size_t off = 0;
  float* dinv = ws + off; off += (size_t)N;
  if (off & 1) off++;                       // 8B-align what follows
  float* h    = ws + off; off += (size_t)N * 128;
  int* iws = (int*)(ws + off);              // 8B-aligned
  size_t ioff = 0;
  int2* csr    = (int2*)iws; ioff += (size_t)2 * E;
  int* cnt     = iws + ioff; ioff += (size_t)N;
  int* partial = iws + ioff; ioff += (size_t)N;
  int* bsum    = iws + ioff; ioff += 512;
  int* rowptr  = iws + ioff; ioff += (size_t)N + 1;
  ioff = (ioff + 3) & ~(size_t)3;           // 16B-align ushort area
  unsigned short* usws = (unsigned short*)(iws + ioff);
  size_t uoff = 0;
  unsigned short* xh_bf  = usws + uoff; uoff += (size_t)N * 128;
  unsigned short* xw_bf  = usws + uoff; uoff += (size_t)N * 128;
  unsigned short* linWp  = usws + uoff; uoff += 128 * 128;
  unsigned short* convWp = usws + uoff; uoff += 3 * 128 * 128;
  unsigned short* Bi     = usws + uoff; uoff += 384 * 128;
  unsigned short* Bh     = usws + uoff; uoff += 384 * 128;

  // pos[E] aliases xw_bf (pos dies at k_fill; xw first written by conv0)
  int* pos = (int*)xw_bf;

  int gw4  = (N + 63) / 64;         // 4 waves x 16 rows per block
  int nCnt = (E + 255) / 256;
  int n512 = (N + 511) / 512;
  int e512 = (E + 511) / 512;
  int ggat = (N + 3) / 4;           // 1 node/wave, 4 waves/block

  // 1) packs + zero cnt
  k_prep<<<80 + nb, 256, 0, stream>>>(linW, convW, Wih, Whh,
                                      linWp, convWp, Bi, Bh, cnt, N);
  // 2) count+pos || xh = relu(x@linW + linB)
  k_count_lin<<<nCnt + gw4, 256, 0, stream>>>(dstI, cnt, pos, E,
                                              x, linWp, linB, xh_bf, N, nCnt);
  // 3-4) rowptr scan (sums merged into add)
  k_scan_block<<<nb, 256, 0, stream>>>(cnt, partial, bsum, N);
  k_scan_add<<<nb, 256, 0, stream>>>(partial, bsum, rowptr, N, nb);
  // 5) csr fill (atomic-free, raw weights)
  k_fill<<<e512, 512, 0, stream>>>(srcI, dstI, ew, rowptr, pos, csr, E);
  // 6) deg/dinv
  k_deg<<<n512, 512, 0, stream>>>(rowptr, csr, dinv, N);
  // 7) GRU#1 (h0 -> h)
  k_gru<<<gw4, 256, 0, stream>>>(xh_bf, h0, h, Bi, Bh, bih, bhh, N);
  // 8-16) 3x { conv, gather(inline norm), GRU }
  for (int l = 0; l < 3; ++l) {
    k_conv<<<gw4, 256, 0, stream>>>(
        xh_bf, convWp + (size_t)l * 128 * 128, xw_bf, N);
    k_gather<<<ggat, 256, 0, stream>>>(
        rowptr, csr, (const unsigned*)xw_bf, dinv, convB + (size_t)l * 128,
        (unsigned*)xh_bf, N);
    k_gru<<<gw4, 256, 0, stream>>>(xh_bf, h, h, Bi, Bh, bih, bhh, N);
  }
  // 17) out = h @ fcW + fcB (fp32)
  dim3 g40(1, (N + 63) / 64);
  k_gemm128<false, true><<<g40, 256, 0, stream>>>(h, fcW, fcB, (float*)d_out, N, 40);
}